// Round 9
// baseline (457.246 us; speedup 1.0000x reference)
//
#include <hip/hip_runtime.h>
#include <math.h>

// Problem constants
#define BB 2
#define LL 2048
#define DD 2048
#define HH 16
#define KVH 8
#define HDIM 128
#define SCALE_F 0.08838834764831845f   // 128^-0.5
#define EPS_F 1e-5f
#define LOG2E 1.4426950408889634f
#define SMAX_F 17.0f                    // fixed softmax max (log2 domain); |s*SC2| <= 16.5
#define QKVW 4096                       // fused qkv row width: 16q + 8k + 8v heads

typedef unsigned short u16;
typedef __attribute__((ext_vector_type(8))) short short8;
typedef __attribute__((ext_vector_type(4))) float f32x4;
typedef __attribute__((ext_vector_type(16))) float f32x16;

#define MFMA16(a, b, c) __builtin_amdgcn_mfma_f32_16x16x32_bf16((a), (b), (c), 0, 0, 0)
#define MFMA32(a, b, c) __builtin_amdgcn_mfma_f32_32x32x16_bf16((a), (b), (c), 0, 0, 0)

__device__ __forceinline__ float b2f(u16 u) {
    union { unsigned int i; float f; } x;
    x.i = ((unsigned int)u) << 16;
    return x.f;
}
__device__ __forceinline__ u16 f2b(float f) {
    unsigned int x = __float_as_uint(f);
    unsigned int r = x + 0x7FFFu + ((x >> 16) & 1u);   // round-to-nearest-even
    return (u16)(r >> 16);
}
// pack two f32 -> one dword of 2 bf16 (RNE), single VALU op
__device__ __forceinline__ unsigned cvtpk(float lo, float hi) {
    unsigned r;
    asm("v_cvt_pk_bf16_f32 %0, %1, %2" : "=v"(r) : "v"(lo), "v"(hi));
    return r;
}
// swap upper 32 lanes of a with lower 32 lanes of b
__device__ __forceinline__ void pl32swap(unsigned &a, unsigned &b) {
    asm("v_permlane32_swap_b32 %0, %1" : "+v"(a), "+v"(b));
}
// async global->LDS, 16B per lane; LDS dest = base + lane*16 (HW-fixed)
__device__ __forceinline__ void g2l(const u16* g, u16* l) {
    __builtin_amdgcn_global_load_lds(
        (const __attribute__((address_space(1))) unsigned int*)g,
        (__attribute__((address_space(3))) unsigned int*)l, 16, 0, 0);
}

// ---------------------------------------------------------------------------
// Fused prep: [0,8192) x fp32->bf16 | [8192,11264) weight transposes |
// [11264,11776) rope tables. All independent; one launch.
// ---------------------------------------------------------------------------
__global__ __launch_bounds__(256) void prep_kernel(const float* __restrict__ x,
                                                   u16* __restrict__ xb,
                                                   const float* __restrict__ wq,
                                                   const float* __restrict__ wk,
                                                   const float* __restrict__ wv,
                                                   const float* __restrict__ wo,
                                                   u16* __restrict__ wqkvT,
                                                   u16* __restrict__ woT,
                                                   float* __restrict__ ct,
                                                   float* __restrict__ st) {
    __shared__ u16 t[64 * 65];
    const int blk = blockIdx.x, tid = threadIdx.x;
    if (blk < 8192) {
        // convert x -> bf16
        int i = (blk * 256 + tid) * 4;
        float4 v = *(const float4*)(x + i);
        unsigned int p0 = (unsigned int)f2b(v.x) | ((unsigned int)f2b(v.y) << 16);
        unsigned int p1 = (unsigned int)f2b(v.z) | ((unsigned int)f2b(v.w) << 16);
        uint2 pk; pk.x = p0; pk.y = p1;
        *(uint2*)(xb + i) = pk;
    } else if (blk < 11264) {
        // weight transpose+convert: in [R=2048 rows][C cols] -> out [C][2048]
        int j = blk - 8192;
        const float* in; u16* out; int C, bx, by;
        if (j < 1024)      { in = wq; out = wqkvT;                      C = 2048; bx = j & 31; by = j >> 5; }
        else if (j < 1536) { j -= 1024; in = wk; out = wqkvT + (size_t)2048 * DD; C = 1024; bx = j & 15; by = j >> 4; }
        else if (j < 2048) { j -= 1536; in = wv; out = wqkvT + (size_t)3072 * DD; C = 1024; bx = j & 15; by = j >> 4; }
        else               { j -= 2048; in = wo; out = woT;                      C = 2048; bx = j & 31; by = j >> 5; }
        int c0 = bx * 64, r0 = by * 64;
#pragma unroll
        for (int i = 0; i < 16; i++) {
            int idx = tid + i * 256;
            int r = idx >> 6, c = idx & 63;
            t[r * 65 + c] = f2b(in[(size_t)(r0 + r) * C + c0 + c]);
        }
        __syncthreads();
#pragma unroll
        for (int i = 0; i < 16; i++) {
            int idx = tid + i * 256;
            int r = idx >> 6, c = idx & 63;
            out[(size_t)(c0 + r) * DD + r0 + c] = t[c * 65 + r];
        }
    } else {
        // rope tables, numpy fp32 semantics
        int i = (blk - 11264) * 256 + tid;   // i < LL*64
        int pos = i >> 6, d = i & 63;
        float freq = (float)pow(10000.0, (double)d * (1.0 / 64.0));
        float ang = (float)pos * freq;
        double a = (double)ang;
        ct[i] = (float)cos(a);
        st[i] = (float)sin(a);
    }
}

// ---------------------------------------------------------------------------
// QKV GEMM: C[M,N] = A[M,K] @ Bt[N,K]^T, bf16 out. 128x128 tile, BK=64.
// ---------------------------------------------------------------------------
__global__ __launch_bounds__(256) void gemm_bt(const u16* __restrict__ A,
                                               const u16* __restrict__ Bt,
                                               u16* __restrict__ C, int M, int N, int K) {
    __shared__ __align__(16) u16 As[128 * 64];   // 16 KB
    __shared__ __align__(16) u16 Bs[128 * 64];   // 16 KB
    const int tid = threadIdx.x;
    const int w = tid >> 6, lane = tid & 63;
    const int lm = lane & 15, lq = lane >> 4;
    const int bn0 = blockIdx.x * 128, bm0 = blockIdx.y * 128;
    const int wm = (w >> 1) * 64, wn = (w & 1) * 64;

    f32x4 acc[4][4];
#pragma unroll
    for (int i = 0; i < 4; i++)
#pragma unroll
        for (int j = 0; j < 4; j++) acc[i][j] = (f32x4){0.f, 0.f, 0.f, 0.f};

    const int srow = lane >> 3;
    const int sgr = (lane & 7) ^ (srow & 7);
    const u16* ga = A + (size_t)(bm0 + w * 32 + srow) * K + sgr * 8;
    const u16* gb = Bt + (size_t)(bn0 + w * 32 + srow) * K + sgr * 8;
    u16* lA = &As[(w * 32) * 64];
    u16* lB = &Bs[(w * 32) * 64];

    for (int k0 = 0; k0 < K; k0 += 64) {
        __syncthreads();
#pragma unroll
        for (int ch = 0; ch < 4; ch++)
            g2l(ga + (size_t)(ch * 8) * K + k0, lA + ch * 8 * 64);
#pragma unroll
        for (int ch = 0; ch < 4; ch++)
            g2l(gb + (size_t)(ch * 8) * K + k0, lB + ch * 8 * 64);
        __syncthreads();

#pragma unroll
        for (int sub = 0; sub < 2; sub++) {
            short8 af[4], bf[4];
#pragma unroll
            for (int mt = 0; mt < 4; mt++) {
                int row = wm + mt * 16 + lm;
                af[mt] = *(const short8*)(&As[row * 64 + ((sub * 4 + lq) ^ (lm & 7)) * 8]);
            }
#pragma unroll
            for (int nt = 0; nt < 4; nt++) {
                int row = wn + nt * 16 + lm;
                bf[nt] = *(const short8*)(&Bs[row * 64 + ((sub * 4 + lq) ^ (lm & 7)) * 8]);
            }
#pragma unroll
            for (int mt = 0; mt < 4; mt++)
#pragma unroll
                for (int nt = 0; nt < 4; nt++) acc[mt][nt] = MFMA16(af[mt], bf[nt], acc[mt][nt]);
        }
    }

#pragma unroll
    for (int mt = 0; mt < 4; mt++)
#pragma unroll
        for (int nt = 0; nt < 4; nt++)
#pragma unroll
            for (int r = 0; r < 4; r++) {
                int row = bm0 + wm + mt * 16 + lq * 4 + r;
                int col = bn0 + wn + nt * 16 + lm;
                C[(size_t)row * N + col] = f2b(acc[mt][nt][r]);
            }
}

// ---------------------------------------------------------------------------
// Output GEMM: 64x128 tile, BK=64, fp32 direct store. Grid (16,64) = 1024
// blocks = 4/CU; LDS 24KB.
// ---------------------------------------------------------------------------
__global__ __launch_bounds__(256) void gemm_bt_o(const u16* __restrict__ A,
                                                 const u16* __restrict__ Bt,
                                                 float* __restrict__ C, int M, int N, int K) {
    __shared__ __align__(16) u16 As[64 * 64];    // 8 KB
    __shared__ __align__(16) u16 Bs[128 * 64];   // 16 KB
    const int tid = threadIdx.x;
    const int w = tid >> 6, lane = tid & 63;
    const int lm = lane & 15, lq = lane >> 4;
    const int bn0 = blockIdx.x * 128, bm0 = blockIdx.y * 64;
    const int wm = (w >> 1) * 32, wn = (w & 1) * 64;

    f32x4 acc[2][4];
#pragma unroll
    for (int i = 0; i < 2; i++)
#pragma unroll
        for (int j = 0; j < 4; j++) acc[i][j] = (f32x4){0.f, 0.f, 0.f, 0.f};

    const int srow = lane >> 3;
    const int sgr = (lane & 7) ^ (srow & 7);
    const u16* ga = A + (size_t)(bm0 + w * 16 + srow) * K + sgr * 8;   // 16 A-rows/wave
    const u16* gb = Bt + (size_t)(bn0 + w * 32 + srow) * K + sgr * 8;  // 32 B-rows/wave
    u16* lA = &As[(w * 16) * 64];
    u16* lB = &Bs[(w * 32) * 64];

    for (int k0 = 0; k0 < K; k0 += 64) {
        __syncthreads();
#pragma unroll
        for (int ch = 0; ch < 2; ch++)
            g2l(ga + (size_t)(ch * 8) * K + k0, lA + ch * 8 * 64);
#pragma unroll
        for (int ch = 0; ch < 4; ch++)
            g2l(gb + (size_t)(ch * 8) * K + k0, lB + ch * 8 * 64);
        __syncthreads();

#pragma unroll
        for (int sub = 0; sub < 2; sub++) {
            short8 af[2], bf[4];
#pragma unroll
            for (int mt = 0; mt < 2; mt++) {
                int row = wm + mt * 16 + lm;
                af[mt] = *(const short8*)(&As[row * 64 + ((sub * 4 + lq) ^ (lm & 7)) * 8]);
            }
#pragma unroll
            for (int nt = 0; nt < 4; nt++) {
                int row = wn + nt * 16 + lm;
                bf[nt] = *(const short8*)(&Bs[row * 64 + ((sub * 4 + lq) ^ (lm & 7)) * 8]);
            }
#pragma unroll
            for (int mt = 0; mt < 2; mt++)
#pragma unroll
                for (int nt = 0; nt < 4; nt++) acc[mt][nt] = MFMA16(af[mt], bf[nt], acc[mt][nt]);
        }
    }

#pragma unroll
    for (int mt = 0; mt < 2; mt++)
#pragma unroll
        for (int nt = 0; nt < 4; nt++)
#pragma unroll
            for (int r = 0; r < 4; r++) {
                int row = bm0 + wm + mt * 16 + lq * 4 + r;
                int col = bn0 + wn + nt * 16 + lm;
                C[(size_t)row * N + col] = acc[mt][nt][r];
            }
}

// ---------------------------------------------------------------------------
// Fused RoPE+RMSNorm (blocks [0,24576)) + V transpose (blocks [24576,25600)).
// ---------------------------------------------------------------------------
__global__ __launch_bounds__(256) void ropetv_kernel(u16* __restrict__ qkv,
                                                     u16* __restrict__ vt,
                                                     const float* __restrict__ qw,
                                                     const float* __restrict__ kw,
                                                     const float* __restrict__ ct,
                                                     const float* __restrict__ st) {
    __shared__ u16 t[64 * 65];
    const int blk = blockIdx.x, tid = threadIdx.x;
    if (blk < 24576) {
        int slot = blk * 4 + (tid >> 6);
        int lane = tid & 63;
        int hh = slot % (HH + KVH);
        int row = slot / (HH + KVH);   // [0, B*L)
        int pos = row & (LL - 1);

        u16* base = qkv + (size_t)row * QKVW + hh * HDIM;
        const float* w = (hh < HH) ? qw : kw;

        float x1 = b2f(base[lane]), x2 = b2f(base[lane + 64]);
        float c = ct[pos * 64 + lane], s = st[pos * 64 + lane];
        float r1 = x1 * c - x2 * s;
        float r2 = x2 * c + x1 * s;
        float ss = r1 * r1 + r2 * r2;
#pragma unroll
        for (int m = 1; m < 64; m <<= 1) ss += __shfl_xor(ss, m, 64);
        float sc = 1.0f / sqrtf(ss * (1.0f / 128.0f) + EPS_F);
        base[lane] = f2b(r1 * sc * w[lane]);
        base[lane + 64] = f2b(r2 * sc * w[lane + 64]);
    } else {
        // V cols of qkv (3072 + g*128 + d) -> vt [b*8+g][d][l]
        int j = blk - 24576;
        int bx = j & 31, by = (j >> 5) & 1, bg = j >> 6;
        int l0 = bx * 64, d0 = by * 64;
        int b = bg >> 3, g = bg & 7;
        const u16* src = qkv + (size_t)b * LL * QKVW + 3072 + g * HDIM;
        u16* dst = vt + (size_t)bg * HDIM * LL;
#pragma unroll
        for (int i = 0; i < 16; i++) {
            int idx = tid + i * 256;
            int r = idx >> 6, c = idx & 63;
            t[r * 65 + c] = src[(size_t)(l0 + r) * QKVW + d0 + c];
        }
        __syncthreads();
#pragma unroll
        for (int i = 0; i < 16; i++) {
            int idx = tid + i * 256;
            int r = idx >> 6, c = idx & 63;   // r = dim, c = key
            dst[(size_t)(d0 + r) * LL + l0 + c] = t[c * 65 + r];
        }
    }
}

// ---------------------------------------------------------------------------
// Flash attention, 32x32x16 MFMA, fixed-max softmax, in-register P transpose.
// Round-2 structure + round-5 XCD swizzle (both verified, 95.5 us).
// Round-9 single change: NO V LDS STAGING. After the XCD swizzle each XCD's
// K/V working set is 2MB = L2-resident (FETCH 16.7MB confirms), so staging V
// into LDS (reuse factor only 2) is pure overhead (guide common-mistake #7).
// PV reads V directly from global/L2 as the MFMA B-operand; V addresses
// depend only on t, so loads issue at tile top and QK^T+softmax (~700cyc)
// covers the ~200cyc L2 latency. Removes STAGEV + barrier (b) + vmcnt(4):
// ONE barrier per tile. LDS 48 -> 34.5KB -> grid-limited 4 blocks/CU (was 3).
// Dual-acc NOT used (round-8: +16 acc regs spills ~11MB/dispatch to scratch).
// ---------------------------------------------------------------------------
__global__ __launch_bounds__(256, 3) void attn_kernel(const u16* __restrict__ qkv,
                                                      const u16* __restrict__ vt,
                                                      u16* __restrict__ ob) {
    // Kt dbuf 2x64x128 u16 = 32768 B; final combine overlay needs 35328 B.
    __shared__ __align__(16) u16 SM[17664];   // 35328 B

    const int tid = threadIdx.x, w = tid >> 6, lane = tid & 63;
    const int l31 = lane & 31, lh = lane >> 5;
    const int qh = w & 1, kh = w >> 1;          // q-half, key-half

    // XCD swizzle: 1024 blocks, HW round-robins bid%8 -> XCD. Give XCD c
    // bh in [c*4, c*4+4) and all 32 q-tiles. Bijective (1024 % 8 == 0).
    const int bid = blockIdx.y * 32 + blockIdx.x;
    const int xcd = bid & 7, idx = bid >> 3;    // idx in [0,128)
    const int bh = xcd * 4 + (idx >> 5);
    const int q0 = (idx & 31) * 64;
    const int b = bh >> 4, hd = bh & 15, g = hd >> 1;

    const u16* kbase = qkv + (size_t)b * LL * QKVW + 2048 + g * HDIM;
    const u16* vtbase = vt + (size_t)(b * KVH + g) * HDIM * LL;

    const int krl = lane >> 4, kgl = lane & 15;

#define STAGEK(tt, bi) do {                                                  \
        _Pragma("unroll")                                                    \
        for (int ch = 0; ch < 4; ch++) {                                     \
            int r_ = w * 16 + ch * 4 + krl;                                  \
            int gc_ = kgl ^ (r_ & 15);                                       \
            g2l(kbase + (size_t)((tt) * 64 + r_) * QKVW + gc_ * 8,           \
                SM + (bi) * 8192 + (w * 16 + ch * 4) * 128);                 \
        }                                                                    \
    } while (0)

    // Q fragments; B-operand of 32x32x16: n = l31 -> q-row, k = kk*16+lh*8+j
    const int qrow = q0 + qh * 32 + l31;
    short8 aq[8];
    {
        const u16* qp = qkv + (size_t)(b * LL + qrow) * QKVW + hd * HDIM + lh * 8;
#pragma unroll
        for (int kk = 0; kk < 8; kk++) aq[kk] = *(const short8*)(qp + kk * 16);
    }

    // per-lane V base: row = dim (added per dn), col = key offset within row
    // key_local = kc*16 + lh*8; kc = kh*2 + kcl
    const u16* vbase = vtbase + (size_t)l31 * LL + kh * 32 + lh * 8;

    f32x16 o[4];
#pragma unroll
    for (int i = 0; i < 4; i++)
#pragma unroll
        for (int r = 0; r < 16; r++) o[i][r] = 0.f;
    float psum = 0.f;
    const float SC2 = SCALE_F * LOG2E;
    const f32x16 fz = {};   // hoisted zero acc

    STAGEK(0, 0);
    asm volatile("s_waitcnt vmcnt(0)" ::: "memory");
    __builtin_amdgcn_s_barrier();

    for (int t = 0; t < LL / 64; t++) {
        const int cur = t & 1;
        const u16* Kc = SM + cur * 8192;
        STAGEK((t + 1) & (LL / 64 - 1), cur ^ 1);

        // S^T = K @ Q^T over this wave's 32-key half: col = q-row = l31,
        // row = key-local (r&3)+8*(r>>2)+4*lh
        const int key = kh * 32 + l31;
        f32x16 s;
        __builtin_amdgcn_s_setprio(1);
        {
            int gg = lh ^ (key & 15);
            short8 kf = *(const short8*)(&Kc[key * 128 + gg * 8]);
            s = MFMA32(kf, aq[0], fz);
        }
#pragma unroll
        for (int kk = 1; kk < 8; kk++) {
            int gg = (kk * 2 + lh) ^ (key & 15);
            short8 kf = *(const short8*)(&Kc[key * 128 + gg * 8]);
            s = MFMA32(kf, aq[kk], s);
        }
        __builtin_amdgcn_s_setprio(0);

        // softmax + pack to bf16 A-fragments (in-register, permlane32_swap)
        float p[16];
#pragma unroll
        for (int r = 0; r < 16; r++) {
            p[r] = __builtin_amdgcn_exp2f(fmaf(s[r], SC2, -SMAX_F));
            psum += p[r];
        }
        unsigned pw[2][4];
#pragma unroll
        for (int half = 0; half < 2; half++) {
            int qb = half * 8;
            unsigned c0 = cvtpk(p[qb + 0], p[qb + 1]);
            unsigned c1 = cvtpk(p[qb + 2], p[qb + 3]);
            unsigned c2 = cvtpk(p[qb + 4], p[qb + 5]);
            unsigned c3 = cvtpk(p[qb + 6], p[qb + 7]);
            pl32swap(c0, c2);
            pl32swap(c1, c3);
            pw[half][0] = c0; pw[half][1] = c1; pw[half][2] = c2; pw[half][3] = c3;
        }

        // O += P @ V; V read directly from global (L2-resident).
        // B-operand element [k][n]: n = d = dn*32 + l31, k-slice key offset
        // kc*16 + lh*8 + j  ->  vbase + dn*32 rows + kcl*16 + t*64.
        __builtin_amdgcn_s_setprio(1);
#pragma unroll
        for (int kcl = 0; kcl < 2; kcl++) {
            union { unsigned u[4]; short8 s8; } pu;
#pragma unroll
            for (int i = 0; i < 4; i++) pu.u[i] = pw[kcl][i];
#pragma unroll
            for (int dn = 0; dn < 4; dn++) {
                short8 bv = *(const short8*)(vbase + (size_t)(dn * 32) * LL +
                                             t * 64 + kcl * 16);
                o[dn] = MFMA32(pu.s8, bv, o[dn]);
            }
        }
        __builtin_amdgcn_s_setprio(0);

        // K(t+1) landed; all reads of Kc done -> next iter may overwrite
        asm volatile("s_waitcnt vmcnt(0)" ::: "memory");
        __builtin_amdgcn_s_barrier();
    }
#undef STAGEK

    // combine the two lh halves of this wave's key-half partial row sums
    psum += __shfl_xor(psum, 32, 64);

    // combine key-halves across wave pairs (w, w+2) via LDS (reuse SM)
    __syncthreads();
    float* xo = (float*)SM;             // [2][64][68] floats = 34816 B
    float* xp = xo + 2 * 64 * 68;       // [2][64] = 512 B
    if (kh == 1) {
        float* dst = xo + (qh * 64 + lane) * 68;
#pragma unroll
        for (int dn = 0; dn < 4; dn++)
#pragma unroll
            for (int r = 0; r < 16; r += 4)
                *(f32x4*)(dst + dn * 16 + r) =
                    (f32x4){o[dn][r], o[dn][r + 1], o[dn][r + 2], o[dn][r + 3]};
        xp[qh * 64 + lane] = psum;
    }
    __syncthreads();
    if (kh == 0) {
        const float* src = xo + (qh * 64 + lane) * 68;
        float inv = 1.0f / (psum + xp[qh * 64 + lane]);
        float invr[16];
#pragma unroll
        for (int r = 0; r < 16; r++) {
            int row = (r & 3) + 8 * (r >> 2) + 4 * lh;
            invr[r] = __shfl(inv, row, 32);
        }
        // O: col = dim = dn*32 + l31, row = (r&3)+8*(r>>2)+4*lh
        u16* obase = ob + (size_t)(b * LL + q0 + qh * 32) * (HH * HDIM) + hd * HDIM;
#pragma unroll
        for (int dn = 0; dn < 4; dn++)
#pragma unroll
            for (int r = 0; r < 16; r++) {
                int row = (r & 3) + 8 * (r >> 2) + 4 * lh;
                float v = o[dn][r] + src[dn * 16 + r];
                obase[(size_t)row * (HH * HDIM) + dn * 32 + l31] = f2b(v * invr[r]);
            }
    }
}

// ---------------------------------------------------------------------------
extern "C" void kernel_launch(void* const* d_in, const int* in_sizes, int n_in,
                              void* d_out, int out_size, void* d_ws, size_t ws_size,
                              hipStream_t stream) {
    const float* x  = (const float*)d_in[0];
    const float* wq = (const float*)d_in[1];
    const float* wk = (const float*)d_in[2];
    const float* wv = (const float*)d_in[3];
    const float* wo = (const float*)d_in[4];
    const float* qn = (const float*)d_in[5];
    const float* kn = (const float*)d_in[6];

    u16* ws = (u16*)d_ws;
    const size_t SZ_X = (size_t)BB * LL * DD;          // 8388608
    u16* xb    = ws;                         // SZ_X (later reused as att)
    u16* qkv   = xb + SZ_X;                  // B*L*4096 = 16.8M
    u16* wqkvT = qkv + (size_t)BB * LL * QKVW;  // 4096*2048 (later reused as vt)
    u16* woT   = wqkvT + (size_t)QKVW * DD;  // 2048*2048
    float* ct  = (float*)(woT + (size_t)DD * DD);   // LL*64 floats
    float* st  = ct + (size_t)LL * 64;
    u16* att = xb;
    u16* vt  = wqkvT;   // dead after fused QKV GEMM

    // 1. fused prep: x convert + 4 weight transposes + rope tables
    prep_kernel<<<dim3(11776), dim3(256), 0, stream>>>(x, xb, wq, wk, wv, wo,
                                                       wqkvT, woT, ct, st);
    // 2. fused QKV projection: [B*L, 4096] = xb @ wqkvT^T  (BK=64)
    gemm_bt<<<dim3(QKVW / 128, BB * LL / 128), dim3(256), 0, stream>>>(xb, wqkvT, qkv, BB * LL, QKVW, DD);
    // 3. fused rope+rmsnorm (q,k) + V transpose
    ropetv_kernel<<<dim3(25600), dim3(256), 0, stream>>>(qkv, vt, qn, kn, ct, st);
    // 4. attention: round-2 structure + XCD swizzle + V-direct-from-L2
    attn_kernel<<<dim3(LL / 64, BB * HH), dim3(256), 0, stream>>>(qkv, vt, att);
    // 5. output projection: 64x128 tile, BK=64, 1024 blocks = 4/CU, fp32 store
    gemm_bt_o<<<dim3(DD / 128, BB * LL / 64), dim3(256), 0, stream>>>(att, woT, (float*)d_out, BB * LL, DD, DD);
}

// Round 10
// 353.932 us; speedup vs baseline: 1.2919x; 1.2919x over previous
//
#include <hip/hip_runtime.h>
#include <math.h>

// Problem constants
#define BB 2
#define LL 2048
#define DD 2048
#define HH 16
#define KVH 8
#define HDIM 128
#define SCALE_F 0.08838834764831845f   // 128^-0.5
#define EPS_F 1e-5f
#define LOG2E 1.4426950408889634f
#define SMAX_F 17.0f                    // fixed softmax max (log2 domain); |s*SC2| <= 16.5
#define QKVW 4096                       // fused qkv row width: 16q + 8k + 8v heads

typedef unsigned short u16;
typedef __attribute__((ext_vector_type(8))) short short8;
typedef __attribute__((ext_vector_type(4))) float f32x4;
typedef __attribute__((ext_vector_type(16))) float f32x16;

#define MFMA16(a, b, c) __builtin_amdgcn_mfma_f32_16x16x32_bf16((a), (b), (c), 0, 0, 0)
#define MFMA32(a, b, c) __builtin_amdgcn_mfma_f32_32x32x16_bf16((a), (b), (c), 0, 0, 0)

__device__ __forceinline__ float b2f(u16 u) {
    union { unsigned int i; float f; } x;
    x.i = ((unsigned int)u) << 16;
    return x.f;
}
__device__ __forceinline__ u16 f2b(float f) {
    unsigned int x = __float_as_uint(f);
    unsigned int r = x + 0x7FFFu + ((x >> 16) & 1u);   // round-to-nearest-even
    return (u16)(r >> 16);
}
// pack two f32 -> one dword of 2 bf16 (RNE), single VALU op
__device__ __forceinline__ unsigned cvtpk(float lo, float hi) {
    unsigned r;
    asm("v_cvt_pk_bf16_f32 %0, %1, %2" : "=v"(r) : "v"(lo), "v"(hi));
    return r;
}
// swap upper 32 lanes of a with lower 32 lanes of b
__device__ __forceinline__ void pl32swap(unsigned &a, unsigned &b) {
    asm("v_permlane32_swap_b32 %0, %1" : "+v"(a), "+v"(b));
}
// async global->LDS, 16B per lane; LDS dest = base + lane*16 (HW-fixed)
__device__ __forceinline__ void g2l(const u16* g, u16* l) {
    __builtin_amdgcn_global_load_lds(
        (const __attribute__((address_space(1))) unsigned int*)g,
        (__attribute__((address_space(3))) unsigned int*)l, 16, 0, 0);
}

// ---------------------------------------------------------------------------
// Fused prep: [0,8192) x fp32->bf16 | [8192,11264) weight transposes |
// [11264,11776) rope tables. All independent; one launch.
// ---------------------------------------------------------------------------
__global__ __launch_bounds__(256) void prep_kernel(const float* __restrict__ x,
                                                   u16* __restrict__ xb,
                                                   const float* __restrict__ wq,
                                                   const float* __restrict__ wk,
                                                   const float* __restrict__ wv,
                                                   const float* __restrict__ wo,
                                                   u16* __restrict__ wqkvT,
                                                   u16* __restrict__ woT,
                                                   float* __restrict__ ct,
                                                   float* __restrict__ st) {
    __shared__ u16 t[64 * 65];
    const int blk = blockIdx.x, tid = threadIdx.x;
    if (blk < 8192) {
        // convert x -> bf16
        int i = (blk * 256 + tid) * 4;
        float4 v = *(const float4*)(x + i);
        unsigned int p0 = (unsigned int)f2b(v.x) | ((unsigned int)f2b(v.y) << 16);
        unsigned int p1 = (unsigned int)f2b(v.z) | ((unsigned int)f2b(v.w) << 16);
        uint2 pk; pk.x = p0; pk.y = p1;
        *(uint2*)(xb + i) = pk;
    } else if (blk < 11264) {
        // weight transpose+convert: in [R=2048 rows][C cols] -> out [C][2048]
        int j = blk - 8192;
        const float* in; u16* out; int C, bx, by;
        if (j < 1024)      { in = wq; out = wqkvT;                      C = 2048; bx = j & 31; by = j >> 5; }
        else if (j < 1536) { j -= 1024; in = wk; out = wqkvT + (size_t)2048 * DD; C = 1024; bx = j & 15; by = j >> 4; }
        else if (j < 2048) { j -= 1536; in = wv; out = wqkvT + (size_t)3072 * DD; C = 1024; bx = j & 15; by = j >> 4; }
        else               { j -= 2048; in = wo; out = woT;                      C = 2048; bx = j & 31; by = j >> 5; }
        int c0 = bx * 64, r0 = by * 64;
#pragma unroll
        for (int i = 0; i < 16; i++) {
            int idx = tid + i * 256;
            int r = idx >> 6, c = idx & 63;
            t[r * 65 + c] = f2b(in[(size_t)(r0 + r) * C + c0 + c]);
        }
        __syncthreads();
#pragma unroll
        for (int i = 0; i < 16; i++) {
            int idx = tid + i * 256;
            int r = idx >> 6, c = idx & 63;
            out[(size_t)(c0 + r) * DD + r0 + c] = t[c * 65 + r];
        }
    } else {
        // rope tables, numpy fp32 semantics
        int i = (blk - 11264) * 256 + tid;   // i < LL*64
        int pos = i >> 6, d = i & 63;
        float freq = (float)pow(10000.0, (double)d * (1.0 / 64.0));
        float ang = (float)pos * freq;
        double a = (double)ang;
        ct[i] = (float)cos(a);
        st[i] = (float)sin(a);
    }
}

// ---------------------------------------------------------------------------
// Fused QKV GEMM + RoPE/RMSNorm + V-transpose epilogue. 128x128 tile, BK=64.
// Each block's 128-col span is exactly one head (bx<16: q, 16<=bx<24: k,
// bx>=24: v head g=bx-24). Epilogue stages the bf16 output tile in LDS
// (same rounding as the old qkv global round-trip -> bit-identical), then:
//   q/k blocks: rope pair (d,d+64) + rmsnorm per row, write roped qkv.
//   v blocks:   write transposed vt[bg][d][l]; skip the qkv write.
// Replaces the separate ropetv kernel (saves ~80MB of L2/HBM round-trip
// traffic + a launch). LDS: staging 32KB, T overlay 34.8KB (aliased).
// ---------------------------------------------------------------------------
__global__ __launch_bounds__(256) void gemm_qkv(const u16* __restrict__ A,
                                                const u16* __restrict__ Bt,
                                                u16* __restrict__ qkv,
                                                u16* __restrict__ vt,
                                                const float* __restrict__ qw,
                                                const float* __restrict__ kw,
                                                const float* __restrict__ ct,
                                                const float* __restrict__ st) {
    __shared__ __align__(16) u16 SM[17408];   // 34816 B
    u16* As = SM;              // [128*64] staging
    u16* Bs = SM + 8192;       // [128*64] staging
    const int K = DD, N = QKVW;
    const int tid = threadIdx.x;
    const int w = tid >> 6, lane = tid & 63;
    const int lm = lane & 15, lq = lane >> 4;
    const int bn0 = blockIdx.x * 128, bm0 = blockIdx.y * 128;
    const int wm = (w >> 1) * 64, wn = (w & 1) * 64;

    f32x4 acc[4][4];
#pragma unroll
    for (int i = 0; i < 4; i++)
#pragma unroll
        for (int j = 0; j < 4; j++) acc[i][j] = (f32x4){0.f, 0.f, 0.f, 0.f};

    const int srow = lane >> 3;
    const int sgr = (lane & 7) ^ (srow & 7);
    const u16* ga = A + (size_t)(bm0 + w * 32 + srow) * K + sgr * 8;
    const u16* gb = Bt + (size_t)(bn0 + w * 32 + srow) * K + sgr * 8;
    u16* lA = &As[(w * 32) * 64];
    u16* lB = &Bs[(w * 32) * 64];

    for (int k0 = 0; k0 < K; k0 += 64) {
        __syncthreads();
#pragma unroll
        for (int ch = 0; ch < 4; ch++)
            g2l(ga + (size_t)(ch * 8) * K + k0, lA + ch * 8 * 64);
#pragma unroll
        for (int ch = 0; ch < 4; ch++)
            g2l(gb + (size_t)(ch * 8) * K + k0, lB + ch * 8 * 64);
        __syncthreads();

#pragma unroll
        for (int sub = 0; sub < 2; sub++) {
            short8 af[4], bf[4];
#pragma unroll
            for (int mt = 0; mt < 4; mt++) {
                int row = wm + mt * 16 + lm;
                af[mt] = *(const short8*)(&As[row * 64 + ((sub * 4 + lq) ^ (lm & 7)) * 8]);
            }
#pragma unroll
            for (int nt = 0; nt < 4; nt++) {
                int row = wn + nt * 16 + lm;
                bf[nt] = *(const short8*)(&Bs[row * 64 + ((sub * 4 + lq) ^ (lm & 7)) * 8]);
            }
#pragma unroll
            for (int mt = 0; mt < 4; mt++)
#pragma unroll
                for (int nt = 0; nt < 4; nt++) acc[mt][nt] = MFMA16(af[mt], bf[nt], acc[mt][nt]);
        }
    }

    // ---- epilogue: stage bf16 tile T[128][136] (aliases staging bufs) ----
    __syncthreads();                  // all staging reads done
    u16* T = SM;
#pragma unroll
    for (int mt = 0; mt < 4; mt++)
#pragma unroll
        for (int nt = 0; nt < 4; nt++)
#pragma unroll
            for (int r = 0; r < 4; r++) {
                int row = wm + mt * 16 + lq * 4 + r;
                int col = wn + nt * 16 + lm;
                T[row * 136 + col] = f2b(acc[mt][nt][r]);
            }
    __syncthreads();

    const int bx = blockIdx.x;
    const int row = tid >> 1, h = tid & 1;   // 2 threads per tile row
    if (bx < 24) {
        // rope + rmsnorm; identical math/rounding to old ropetv_kernel
        const float* wgt = (bx < 16) ? qw : kw;
        const int grow = bm0 + row;
        const int pos = grow & (LL - 1);
        const float* crow = ct + pos * 64 + h * 32;
        const float* srw  = st + pos * 64 + h * 32;
        const u16* t1 = &T[row * 136 + h * 32];
        const u16* t2 = t1 + 64;
        float ss = 0.f;
#pragma unroll
        for (int dd = 0; dd < 32; dd++) {
            float x1 = b2f(t1[dd]), x2 = b2f(t2[dd]);
            float c = crow[dd], s = srw[dd];
            float r1 = x1 * c - x2 * s;
            float r2 = x2 * c + x1 * s;
            ss += r1 * r1 + r2 * r2;
        }
        ss += __shfl_xor(ss, 1, 64);     // combine the two half-row threads
        float sc = 1.0f / sqrtf(ss * (1.0f / 128.0f) + EPS_F);
        u16* out = qkv + (size_t)grow * QKVW + bx * 128 + h * 32;
#pragma unroll
        for (int dd = 0; dd < 32; dd += 2) {
            float x1a = b2f(t1[dd]),     x2a = b2f(t2[dd]);
            float x1b = b2f(t1[dd + 1]), x2b = b2f(t2[dd + 1]);
            float ca = crow[dd],     sa = srw[dd];
            float cb = crow[dd + 1], sb = srw[dd + 1];
            float r1a = x1a * ca - x2a * sa, r2a = x2a * ca + x1a * sa;
            float r1b = x1b * cb - x2b * sb, r2b = x2b * cb + x1b * sb;
            int d = h * 32 + dd;
            unsigned p1 = (unsigned)f2b(r1a * sc * wgt[d]) |
                          ((unsigned)f2b(r1b * sc * wgt[d + 1]) << 16);
            unsigned p2 = (unsigned)f2b(r2a * sc * wgt[d + 64]) |
                          ((unsigned)f2b(r2b * sc * wgt[d + 65]) << 16);
            *(unsigned*)(out + dd) = p1;
            *(unsigned*)(out + 64 + dd) = p2;
        }
    } else {
        // V head: transposed write vt[(b*8+g)][d][l]; skip qkv write
        const int g = bx - 24;
        const int b = bm0 >> 11;             // batch (blocks never cross)
        const int d = row;
        u16* dst = vt + ((size_t)(b * KVH + g) * HDIM + d) * LL +
                   (bm0 & (LL - 1)) + h * 64;
        const u16* src = &T[(h * 64) * 136 + d];
#pragma unroll
        for (int j = 0; j < 64; j += 2) {
            unsigned pk = (unsigned)src[j * 136] |
                          ((unsigned)src[(j + 1) * 136] << 16);
            *(unsigned*)(dst + j) = pk;
        }
    }
}

// ---------------------------------------------------------------------------
// Output GEMM: 64x128 tile, BK=64, fp32 direct store. Grid (16,64) = 1024
// blocks = 4/CU; LDS 24KB.
// ---------------------------------------------------------------------------
__global__ __launch_bounds__(256) void gemm_bt_o(const u16* __restrict__ A,
                                                 const u16* __restrict__ Bt,
                                                 float* __restrict__ C, int M, int N, int K) {
    __shared__ __align__(16) u16 As[64 * 64];    // 8 KB
    __shared__ __align__(16) u16 Bs[128 * 64];   // 16 KB
    const int tid = threadIdx.x;
    const int w = tid >> 6, lane = tid & 63;
    const int lm = lane & 15, lq = lane >> 4;
    const int bn0 = blockIdx.x * 128, bm0 = blockIdx.y * 64;
    const int wm = (w >> 1) * 32, wn = (w & 1) * 64;

    f32x4 acc[2][4];
#pragma unroll
    for (int i = 0; i < 2; i++)
#pragma unroll
        for (int j = 0; j < 4; j++) acc[i][j] = (f32x4){0.f, 0.f, 0.f, 0.f};

    const int srow = lane >> 3;
    const int sgr = (lane & 7) ^ (srow & 7);
    const u16* ga = A + (size_t)(bm0 + w * 16 + srow) * K + sgr * 8;   // 16 A-rows/wave
    const u16* gb = Bt + (size_t)(bn0 + w * 32 + srow) * K + sgr * 8;  // 32 B-rows/wave
    u16* lA = &As[(w * 16) * 64];
    u16* lB = &Bs[(w * 32) * 64];

    for (int k0 = 0; k0 < K; k0 += 64) {
        __syncthreads();
#pragma unroll
        for (int ch = 0; ch < 2; ch++)
            g2l(ga + (size_t)(ch * 8) * K + k0, lA + ch * 8 * 64);
#pragma unroll
        for (int ch = 0; ch < 4; ch++)
            g2l(gb + (size_t)(ch * 8) * K + k0, lB + ch * 8 * 64);
        __syncthreads();

#pragma unroll
        for (int sub = 0; sub < 2; sub++) {
            short8 af[2], bf[4];
#pragma unroll
            for (int mt = 0; mt < 2; mt++) {
                int row = wm + mt * 16 + lm;
                af[mt] = *(const short8*)(&As[row * 64 + ((sub * 4 + lq) ^ (lm & 7)) * 8]);
            }
#pragma unroll
            for (int nt = 0; nt < 4; nt++) {
                int row = wn + nt * 16 + lm;
                bf[nt] = *(const short8*)(&Bs[row * 64 + ((sub * 4 + lq) ^ (lm & 7)) * 8]);
            }
#pragma unroll
            for (int mt = 0; mt < 2; mt++)
#pragma unroll
                for (int nt = 0; nt < 4; nt++) acc[mt][nt] = MFMA16(af[mt], bf[nt], acc[mt][nt]);
        }
    }

#pragma unroll
    for (int mt = 0; mt < 2; mt++)
#pragma unroll
        for (int nt = 0; nt < 4; nt++)
#pragma unroll
            for (int r = 0; r < 4; r++) {
                int row = bm0 + wm + mt * 16 + lq * 4 + r;
                int col = bn0 + wn + nt * 16 + lm;
                C[(size_t)row * N + col] = acc[mt][nt][r];
            }
}

// ---------------------------------------------------------------------------
// Flash attention, 32x32x16 MFMA, fixed-max softmax, in-register P transpose.
// Round-6 verbatim (verified 95.5 us): round-2 structure (QBLK=64, 4 waves =
// q-half x key-half, Kt dbuf + Vt single, counted vmcnt) + round-5 XCD
// swizzle (FETCH 74.8 -> 16.7 MB). Known-dead variants: dual-acc (spills),
// V-direct-from-L2 (uncoalesced gather), 8-wave geometry (reg-infeasible).
// ---------------------------------------------------------------------------
__global__ __launch_bounds__(256, 3) void attn_kernel(const u16* __restrict__ qkv,
                                                      const u16* __restrict__ vt,
                                                      u16* __restrict__ ob) {
    __shared__ __align__(16) u16 SM[2 * 64 * 128 + 128 * 64];   // 48 KB
    u16* Vt = SM + 2 * 64 * 128;

    const int tid = threadIdx.x, w = tid >> 6, lane = tid & 63;
    const int l31 = lane & 31, lh = lane >> 5;
    const int qh = w & 1, kh = w >> 1;          // q-half, key-half

    // XCD swizzle: 1024 blocks, HW round-robins bid%8 -> XCD. Give XCD c
    // bh in [c*4, c*4+4) and all 32 q-tiles. Bijective (1024 % 8 == 0).
    const int bid = blockIdx.y * 32 + blockIdx.x;
    const int xcd = bid & 7, idx = bid >> 3;    // idx in [0,128)
    const int bh = xcd * 4 + (idx >> 5);
    const int q0 = (idx & 31) * 64;
    const int b = bh >> 4, hd = bh & 15, g = hd >> 1;

    const u16* kbase = qkv + (size_t)b * LL * QKVW + 2048 + g * HDIM;
    const u16* vtbase = vt + (size_t)(b * KVH + g) * HDIM * LL;

    const int krl = lane >> 4, kgl = lane & 15;
    const int vrl = lane >> 3, vgl = lane & 7;

#define STAGEK(tt, bi) do {                                                  \
        _Pragma("unroll")                                                    \
        for (int ch = 0; ch < 4; ch++) {                                     \
            int r_ = w * 16 + ch * 4 + krl;                                  \
            int gc_ = kgl ^ (r_ & 15);                                       \
            g2l(kbase + (size_t)((tt) * 64 + r_) * QKVW + gc_ * 8,           \
                SM + (bi) * 8192 + (w * 16 + ch * 4) * 128);                 \
        }                                                                    \
    } while (0)
#define STAGEV(tt) do {                                                      \
        _Pragma("unroll")                                                    \
        for (int ch = 0; ch < 4; ch++) {                                     \
            int r_ = w * 32 + ch * 8 + vrl;                                  \
            int gc_ = vgl ^ (r_ & 7);                                        \
            g2l(vtbase + (size_t)r_ * LL + (tt) * 64 + gc_ * 8,              \
                Vt + (w * 32 + ch * 8) * 64);                                \
        }                                                                    \
    } while (0)

    // Q fragments; B-operand of 32x32x16: n = l31 -> q-row, k = kk*16+lh*8+j
    const int qrow = q0 + qh * 32 + l31;
    short8 aq[8];
    {
        const u16* qp = qkv + (size_t)(b * LL + qrow) * QKVW + hd * HDIM + lh * 8;
#pragma unroll
        for (int kk = 0; kk < 8; kk++) aq[kk] = *(const short8*)(qp + kk * 16);
    }

    f32x16 o[4];
#pragma unroll
    for (int i = 0; i < 4; i++)
#pragma unroll
        for (int r = 0; r < 16; r++) o[i][r] = 0.f;
    float psum = 0.f;
    const float SC2 = SCALE_F * LOG2E;
    const f32x16 fz = {};   // hoisted zero acc

    STAGEK(0, 0);
    asm volatile("s_waitcnt vmcnt(0)" ::: "memory");
    __builtin_amdgcn_s_barrier();

    for (int t = 0; t < LL / 64; t++) {
        const int cur = t & 1;
        const u16* Kc = SM + cur * 8192;
        // issue order matters for the counted vmcnt: V(t) first, then K(t+1)
        STAGEV(t);
        STAGEK((t + 1) & (LL / 64 - 1), cur ^ 1);

        // S^T = K @ Q^T over this wave's 32-key half: col = q-row = l31,
        // row = key-local (r&3)+8*(r>>2)+4*lh
        const int key = kh * 32 + l31;
        f32x16 s;
        __builtin_amdgcn_s_setprio(1);
        {
            int gg = lh ^ (key & 15);
            short8 kf = *(const short8*)(&Kc[key * 128 + gg * 8]);
            s = MFMA32(kf, aq[0], fz);
        }
#pragma unroll
        for (int kk = 1; kk < 8; kk++) {
            int gg = (kk * 2 + lh) ^ (key & 15);
            short8 kf = *(const short8*)(&Kc[key * 128 + gg * 8]);
            s = MFMA32(kf, aq[kk], s);
        }
        __builtin_amdgcn_s_setprio(0);

        // softmax + pack to bf16 A-fragments (in-register, permlane32_swap)
        float p[16];
#pragma unroll
        for (int r = 0; r < 16; r++) {
            p[r] = __builtin_amdgcn_exp2f(fmaf(s[r], SC2, -SMAX_F));
            psum += p[r];
        }
        unsigned pw[2][4];
#pragma unroll
        for (int half = 0; half < 2; half++) {
            int qb = half * 8;
            unsigned c0 = cvtpk(p[qb + 0], p[qb + 1]);
            unsigned c1 = cvtpk(p[qb + 2], p[qb + 3]);
            unsigned c2 = cvtpk(p[qb + 4], p[qb + 5]);
            unsigned c3 = cvtpk(p[qb + 6], p[qb + 7]);
            pl32swap(c0, c2);
            pl32swap(c1, c3);
            pw[half][0] = c0; pw[half][1] = c1; pw[half][2] = c2; pw[half][3] = c3;
        }

        // V(t) landed (first 4 of 8 outstanding); K(t+1) stays in flight
        asm volatile("s_waitcnt vmcnt(4)" ::: "memory");
        __builtin_amdgcn_s_barrier();

        // O += P @ V over this wave's 2 k-slices
        __builtin_amdgcn_s_setprio(1);
#pragma unroll
        for (int kcl = 0; kcl < 2; kcl++) {
            int kc = kh * 2 + kcl;
            union { unsigned u[4]; short8 s8; } pu;
#pragma unroll
            for (int i = 0; i < 4; i++) pu.u[i] = pw[kcl][i];
#pragma unroll
            for (int dn = 0; dn < 4; dn++) {
                int d = dn * 32 + l31;
                int gv = ((kc * 2 + lh) ^ (d & 7)) * 8;
                short8 bv = *(const short8*)(&Vt[d * 64 + gv]);
                o[dn] = MFMA32(pu.s8, bv, o[dn]);
            }
        }
        __builtin_amdgcn_s_setprio(0);

        // K(t+1) landed; all PV reads of Vt done -> next iter may overwrite
        asm volatile("s_waitcnt vmcnt(0)" ::: "memory");
        __builtin_amdgcn_s_barrier();
    }
#undef STAGEK
#undef STAGEV

    // combine the two lh halves of this wave's key-half partial row sums
    psum += __shfl_xor(psum, 32, 64);

    // combine key-halves across wave pairs (w, w+2) via LDS (reuse SM)
    __syncthreads();
    float* xo = (float*)SM;             // [2][64][68] floats = 34816 B
    float* xp = xo + 2 * 64 * 68;       // [2][64]
    if (kh == 1) {
        float* dst = xo + (qh * 64 + lane) * 68;
#pragma unroll
        for (int dn = 0; dn < 4; dn++)
#pragma unroll
            for (int r = 0; r < 16; r += 4)
                *(f32x4*)(dst + dn * 16 + r) =
                    (f32x4){o[dn][r], o[dn][r + 1], o[dn][r + 2], o[dn][r + 3]};
        xp[qh * 64 + lane] = psum;
    }
    __syncthreads();
    if (kh == 0) {
        const float* src = xo + (qh * 64 + lane) * 68;
        float inv = 1.0f / (psum + xp[qh * 64 + lane]);
        float invr[16];
#pragma unroll
        for (int r = 0; r < 16; r++) {
            int row = (r & 3) + 8 * (r >> 2) + 4 * lh;
            invr[r] = __shfl(inv, row, 32);
        }
        // O: col = dim = dn*32 + l31, row = (r&3)+8*(r>>2)+4*lh
        u16* obase = ob + (size_t)(b * LL + q0 + qh * 32) * (HH * HDIM) + hd * HDIM;
#pragma unroll
        for (int dn = 0; dn < 4; dn++)
#pragma unroll
            for (int r = 0; r < 16; r++) {
                int row = (r & 3) + 8 * (r >> 2) + 4 * lh;
                float v = o[dn][r] + src[dn * 16 + r];
                obase[(size_t)row * (HH * HDIM) + dn * 32 + l31] = f2b(v * invr[r]);
            }
    }
}

// ---------------------------------------------------------------------------
extern "C" void kernel_launch(void* const* d_in, const int* in_sizes, int n_in,
                              void* d_out, int out_size, void* d_ws, size_t ws_size,
                              hipStream_t stream) {
    const float* x  = (const float*)d_in[0];
    const float* wq = (const float*)d_in[1];
    const float* wk = (const float*)d_in[2];
    const float* wv = (const float*)d_in[3];
    const float* wo = (const float*)d_in[4];
    const float* qn = (const float*)d_in[5];
    const float* kn = (const float*)d_in[6];

    u16* ws = (u16*)d_ws;
    const size_t SZ_X = (size_t)BB * LL * DD;          // 8388608
    u16* xb    = ws;                         // SZ_X (later reused as att)
    u16* qkv   = xb + SZ_X;                  // B*L*4096 = 16.8M elems? (u16)
    u16* wqkvT = qkv + (size_t)BB * LL * QKVW;
    u16* woT   = wqkvT + (size_t)QKVW * DD;
    float* ct  = (float*)(woT + (size_t)DD * DD);   // LL*64 floats
    float* st  = ct + (size_t)LL * 64;
    u16* vt    = (u16*)(st + (size_t)LL * 64);      // fresh: 2*8*128*2048 u16
    u16* att = xb;

    // 1. fused prep: x convert + 4 weight transposes + rope tables
    prep_kernel<<<dim3(11776), dim3(256), 0, stream>>>(x, xb, wq, wk, wv, wo,
                                                       wqkvT, woT, ct, st);
    // 2. fused QKV projection + rope/rmsnorm + V-transpose epilogue
    gemm_qkv<<<dim3(QKVW / 128, BB * LL / 128), dim3(256), 0, stream>>>(
        xb, wqkvT, qkv, vt, qn, kn, ct, st);
    // 3. attention: round-6 structure (verified)
    attn_kernel<<<dim3(LL / 64, BB * HH), dim3(256), 0, stream>>>(qkv, vt, att);
    // 4. output projection: 64x128 tile, BK=64, 1024 blocks = 4/CU, fp32 store
    gemm_bt_o<<<dim3(DD / 128, BB * LL / 64), dim3(256), 0, stream>>>(att, woT, (float*)d_out, BB * LL, DD, DD);
}